// Round 2
// baseline (283.614 us; speedup 1.0000x reference)
//
#include <hip/hip_runtime.h>
#include <hip/hip_bf16.h>
#include <cmath>

#define NB 4
#define NM 32
#define DKc 256
#define DVc 32
#define NP 4096

using bf16x8 = __attribute__((ext_vector_type(8))) short;
using f32x4  = __attribute__((ext_vector_type(4))) float;

__device__ __forceinline__ unsigned short f2bf(float f) {
    union { float f; unsigned u; } x; x.f = f;
    unsigned r = 0x7FFFu + ((x.u >> 16) & 1u);
    return (unsigned short)((x.u + r) >> 16);
}
__device__ __forceinline__ float bflo(unsigned u) { union { unsigned u; float f; } x; x.u = u << 16; return x.f; }
__device__ __forceinline__ float bfhi(unsigned u) { union { unsigned u; float f; } x; x.u = u & 0xffff0000u; return x.f; }
__device__ __forceinline__ float bf2f(unsigned short s) { union { unsigned u; float f; } x; x.u = ((unsigned)s) << 16; return x.f; }

// src [R][C] fp32 -> dst [C][R] bf16 (per batch). C,R multiples of 64.
__global__ __launch_bounds__(256) void k_transpose_bf16(
    const float* __restrict__ src, unsigned short* __restrict__ dst,
    int R, int C, long batchStride) {
    __shared__ float tile[64][65];
    int b = blockIdx.z;
    const float* s = src + (long)b * batchStride;
    unsigned short* d = dst + (long)b * batchStride;
    int r0 = blockIdx.y * 64, c0 = blockIdx.x * 64;
    int t = threadIdx.x;
    #pragma unroll
    for (int j = 0; j < 16; ++j) {
        int i = t + 256 * j;
        int r = i >> 6, c = i & 63;
        tile[r][c] = s[(long)(r0 + r) * C + c0 + c];
    }
    __syncthreads();
    #pragma unroll
    for (int j = 0; j < 8; ++j) {
        int i = t + 256 * j;
        int row = i >> 5;   // local output row (along C)
        int pr = i & 31;    // pair index along R
        float f0 = tile[2 * pr][row];
        float f1 = tile[2 * pr + 1][row];
        unsigned pack = (unsigned)f2bf(f0) | ((unsigned)f2bf(f1) << 16);
        reinterpret_cast<unsigned*>(d)[(((long)(c0 + row) * R + r0) >> 1) + pr] = pack;
    }
}

// both 256x256 weight transposes in one dispatch; z=0 -> Q, z=1 -> K
__global__ __launch_bounds__(256) void k_transpose_w2(
    const float* __restrict__ srcQ, unsigned short* __restrict__ dstQ,
    const float* __restrict__ srcK, unsigned short* __restrict__ dstK) {
    __shared__ float tile[64][65];
    const float* s = blockIdx.z ? srcK : srcQ;
    unsigned short* d = blockIdx.z ? dstK : dstQ;
    int r0 = blockIdx.y * 64, c0 = blockIdx.x * 64;
    int t = threadIdx.x;
    #pragma unroll
    for (int j = 0; j < 16; ++j) {
        int i = t + 256 * j;
        int r = i >> 6, c = i & 63;
        tile[r][c] = s[(long)(r0 + r) * 256 + c0 + c];
    }
    __syncthreads();
    #pragma unroll
    for (int j = 0; j < 8; ++j) {
        int i = t + 256 * j;
        int row = i >> 5;
        int pr = i & 31;
        float f0 = tile[2 * pr][row];
        float f1 = tile[2 * pr + 1][row];
        unsigned pack = (unsigned)f2bf(f0) | ((unsigned)f2bf(f1) << 16);
        reinterpret_cast<unsigned*>(d)[(((long)(c0 + row) * 256 + r0) >> 1) + pr] = pack;
    }
}

// vproj[frame][e][p] = sum_d fm[frame][d][p] * V[d][e]
__global__ __launch_bounds__(256) void k_vproj(
    const float* __restrict__ fm, const float* __restrict__ V, float* __restrict__ vproj) {
    __shared__ float Vl[32][32];
    __shared__ float fml[32][256];
    int b = blockIdx.y, p0 = blockIdx.x * 256, t = threadIdx.x;
    #pragma unroll
    for (int j = 0; j < 4; ++j) { int i = t + 256 * j; Vl[i >> 5][i & 31] = V[i]; }
    for (int j = 0; j < 32; ++j) {
        int i = t + 256 * j;
        int dd = i >> 8, c = i & 255;
        fml[dd][c] = fm[((long)b * DVc + dd) * NP + p0 + c];
    }
    __syncthreads();
    float acc[32];
    #pragma unroll
    for (int e = 0; e < 32; ++e) acc[e] = 0.f;
    for (int dd = 0; dd < 32; ++dd) {
        float fv = fml[dd][t];
        #pragma unroll
        for (int e = 0; e < 32; ++e) acc[e] += fv * Vl[dd][e];
    }
    #pragma unroll
    for (int e = 0; e < 32; ++e) vproj[((long)b * DVc + e) * NP + p0 + t] = acc[e];
}

// out[e,p] = sum_d WT[e][d] * fcT[b][p][d]  (bf16 MFMA 16x16x32)
// mat==0 -> qT bf16 [b][p][e];  mat==1 -> kproj fp32 [b][e][p]
__global__ __launch_bounds__(256) void k_proj_gemm(
    const unsigned short* __restrict__ WTq, const unsigned short* __restrict__ WTk,
    const unsigned short* __restrict__ fcT,
    unsigned short* __restrict__ qT, float* __restrict__ kproj) {
    int t = threadIdx.x;
    int wave = t >> 6, lane = t & 63;
    int b = blockIdx.z & 3, mat = blockIdx.z >> 2;
    int e0 = blockIdx.y * 64 + wave * 16;
    int p0 = blockIdx.x * 64;
    int ln = lane & 15, quad = lane >> 4;
    const unsigned short* WT = mat ? WTk : WTq;
    const unsigned short* aptr = WT + (long)(e0 + ln) * DKc + quad * 8;
    const unsigned short* bbase = fcT + ((long)b * NP + p0 + ln) * DKc + quad * 8;
    f32x4 acc[4] = {};
    for (int kk = 0; kk < DKc; kk += 32) {
        bf16x8 a = *reinterpret_cast<const bf16x8*>(aptr + kk);
        #pragma unroll
        for (int j = 0; j < 4; ++j) {
            bf16x8 bb = *reinterpret_cast<const bf16x8*>(bbase + (long)j * 16 * DKc + kk);
            acc[j] = __builtin_amdgcn_mfma_f32_16x16x32_bf16(a, bb, acc[j], 0, 0, 0);
        }
    }
    int eb = e0 + quad * 4;
    if (mat == 0) {
        #pragma unroll
        for (int j = 0; j < 4; ++j)
            #pragma unroll
            for (int r = 0; r < 4; ++r) {
                int e = eb + r, p = p0 + j * 16 + ln;
                qT[((long)b * NP + p) * DKc + e] = f2bf(acc[j][r]);
            }
    } else {
        #pragma unroll
        for (int j = 0; j < 4; ++j)
            #pragma unroll
            for (int r = 0; r < 4; ++r) {
                int e = eb + r, p = p0 + j * 16 + ln;
                kproj[((long)b * DKc + e) * NP + p] = acc[j][r];
            }
    }
}

// scores[b][m][p] = SCALE * sum_e qT[b][p][e] * k[m][e][p]
// block: (p-tile 32, m-quarter of 8). 512 threads: g=t>>5 (e-group of 16), p=t&31.
// grid (128,4) = 512 blocks -> 2 blocks/CU; launch_bounds caps VGPR at 128.
__global__ __launch_bounds__(512, 4) void k_scores(
    const unsigned short* __restrict__ qT, const float* __restrict__ kproj,
    const float* __restrict__ kbuf, float* __restrict__ scores, float scale) {
    __shared__ float red[16][4][4][32];
    int t = threadIdx.x;
    int g = t >> 5, p = t & 31;
    int p0 = blockIdx.x * 32;
    int mg = blockIdx.y;           // 0..3, 8 frames each
    float qreg[4][16];
    #pragma unroll
    for (int b = 0; b < 4; ++b) {
        const uint4* qp4 = reinterpret_cast<const uint4*>(qT + ((long)b * NP + p0 + p) * DKc + g * 16);
        uint4 u0 = qp4[0], u1 = qp4[1];
        unsigned w[8] = {u0.x, u0.y, u0.z, u0.w, u1.x, u1.y, u1.z, u1.w};
        #pragma unroll
        for (int j = 0; j < 8; ++j) { qreg[b][2 * j] = bflo(w[j]); qreg[b][2 * j + 1] = bfhi(w[j]); }
    }
    for (int c = 0; c < 2; ++c) {
        float acc[4][4];
        #pragma unroll
        for (int mi = 0; mi < 4; ++mi)
            #pragma unroll
            for (int b = 0; b < 4; ++b) acc[mi][b] = 0.f;
        #pragma unroll
        for (int mi = 0; mi < 4; ++mi) {
            int m = mg * 8 + c * 4 + mi;
            const float* kp = (m < 4 ? kproj + (long)m * DKc * NP : kbuf + (long)(m - 4) * DKc * NP)
                              + (long)(g * 16) * NP + p0 + p;
            #pragma unroll
            for (int j = 0; j < 16; ++j) {
                float kv = __builtin_nontemporal_load(kp + (long)j * NP);
                acc[mi][0] += qreg[0][j] * kv;
                acc[mi][1] += qreg[1][j] * kv;
                acc[mi][2] += qreg[2][j] * kv;
                acc[mi][3] += qreg[3][j] * kv;
            }
        }
        #pragma unroll
        for (int mi = 0; mi < 4; ++mi)
            #pragma unroll
            for (int b = 0; b < 4; ++b) red[g][mi][b][p] = acc[mi][b];
        __syncthreads();
        {
            int mi = t >> 7, b = (t >> 5) & 3, pp = t & 31;
            float s = 0.f;
            #pragma unroll
            for (int gg = 0; gg < 16; ++gg) s += red[gg][mi][b][pp];
            int m = mg * 8 + c * 4 + mi;
            scores[((long)b * NM + m) * NP + p0 + pp] = scale * s;
        }
        __syncthreads();
    }
}

// softmax over w (rows of 64) + ctx + out = fm + 0.5*ctx
// block: (p-tile 64 = 1 h-row, d-quarter). 256 threads. grid (64,4)=256 blocks.
__global__ __launch_bounds__(256) void k_out(
    const float* __restrict__ scores, const float* __restrict__ vproj,
    const float* __restrict__ vbuf, const float* __restrict__ fm,
    float* __restrict__ out) {
    __shared__ unsigned short attn[128][66];
    int t = threadIdx.x;
    int p0 = blockIdx.x * 64;
    int dq = blockIdx.y;
    {   // phase 1: softmax rows (64 w). 128 rows, 2 threads/row (32 w each).
        int row = t >> 1;            // b*32 + m
        int b = row >> 5, m = row & 31;
        int hs = t & 1;
        const f32x4* s4 = reinterpret_cast<const f32x4*>(scores + ((long)b * NM + m) * NP + p0 + hs * 32);
        f32x4 v[8];
        #pragma unroll
        for (int j = 0; j < 8; ++j) v[j] = s4[j];
        float mx = v[0][0];
        #pragma unroll
        for (int j = 0; j < 8; ++j)
            #pragma unroll
            for (int k = 0; k < 4; ++k) mx = fmaxf(mx, v[j][k]);
        mx = fmaxf(mx, __shfl_xor(mx, 1));
        float sum = 0.f;
        #pragma unroll
        for (int j = 0; j < 8; ++j)
            #pragma unroll
            for (int k = 0; k < 4; ++k) { float e = __expf(v[j][k] - mx); v[j][k] = e; sum += e; }
        sum += __shfl_xor(sum, 1);
        float inv = 1.f / sum;
        unsigned short* arow = &attn[row][hs * 32];
        #pragma unroll
        for (int j = 0; j < 8; ++j)
            #pragma unroll
            for (int k = 0; k < 4; ++k) arow[j * 4 + k] = f2bf(v[j][k] * inv);
    }
    __syncthreads();
    {   // phase 2: ctx + epilogue. px = t&63, b = t>>6.
        int px = t & 63, b = t >> 6;
        float acc[8];
        #pragma unroll
        for (int d = 0; d < 8; ++d) acc[d] = 0.f;
        for (int m = 0; m < 32; ++m) {
            float a = bf2f(attn[b * 32 + m][px]);
            const float* vbp = (m < 4 ? vproj + (long)m * DVc * NP : vbuf + (long)(m - 4) * DVc * NP)
                               + (long)(dq * 8) * NP + p0 + px;
            #pragma unroll
            for (int d = 0; d < 8; ++d) {
                float vv = __builtin_nontemporal_load(vbp + (long)d * NP);
                acc[d] += a * vv;
            }
        }
        #pragma unroll
        for (int d = 0; d < 8; ++d) {
            long i = ((long)b * DVc + dq * 8 + d) * NP + p0 + px;
            out[i] = fm[i] + 0.5f * acc[d];
        }
    }
}

extern "C" void kernel_launch(void* const* d_in, const int* in_sizes, int n_in,
                              void* d_out, int out_size, void* d_ws, size_t ws_size,
                              hipStream_t stream) {
    const float* fc = (const float*)d_in[0];
    const float* fm = (const float*)d_in[1];
    const float* kb = (const float*)d_in[2];
    const float* vb = (const float*)d_in[3];
    const float* Q  = (const float*)d_in[4];
    const float* K  = (const float*)d_in[5];
    const float* V  = (const float*)d_in[6];
    float* out = (float*)d_out;
    char* ws = (char*)d_ws;
    // workspace layout (bytes)
    unsigned short* fcT   = (unsigned short*)(ws);                 // 4*4096*256*2 = 8388608
    unsigned short* WTq   = (unsigned short*)(ws + 8388608);       // 131072
    unsigned short* WTk   = (unsigned short*)(ws + 8519680);       // 131072
    unsigned short* qT    = (unsigned short*)(ws + 8650752);       // 8388608
    float*          kproj = (float*)(ws + 17039360);               // 16777216
    float*          vproj = (float*)(ws + 33816576);               // 2097152
    float*          scores= (float*)(ws + 35913728);               // 2097152
    float scale = (float)(log(135168.0) / log(1000.0) / 16.0);

    hipLaunchKernelGGL(k_transpose_bf16, dim3(64, 4, 4), dim3(256), 0, stream,
                       fc, fcT, 256, 4096, (long)256 * 4096);
    hipLaunchKernelGGL(k_transpose_w2, dim3(4, 4, 2), dim3(256), 0, stream,
                       Q, WTq, K, WTk);
    hipLaunchKernelGGL(k_vproj, dim3(16, 4), dim3(256), 0, stream, fm, V, vproj);
    hipLaunchKernelGGL(k_proj_gemm, dim3(64, 4, 8), dim3(256), 0, stream,
                       WTq, WTk, fcT, qT, kproj);
    hipLaunchKernelGGL(k_scores, dim3(128, 4), dim3(512), 0, stream,
                       qT, kproj, kb, scores, scale);
    hipLaunchKernelGGL(k_out, dim3(64, 4), dim3(256), 0, stream,
                       scores, vproj, vb, fm, out);
}

// Round 3
// 256.963 us; speedup vs baseline: 1.1037x; 1.1037x over previous
//
#include <hip/hip_runtime.h>
#include <hip/hip_bf16.h>
#include <cmath>

#define NB 4
#define NM 32
#define DKc 256
#define DVc 32
#define NP 4096

using bf16x8 = __attribute__((ext_vector_type(8))) short;
using f32x4  = __attribute__((ext_vector_type(4))) float;

__device__ __forceinline__ unsigned short f2bf(float f) {
    union { float f; unsigned u; } x; x.f = f;
    unsigned r = 0x7FFFu + ((x.u >> 16) & 1u);
    return (unsigned short)((x.u + r) >> 16);
}
__device__ __forceinline__ float bf2f(unsigned short s) { union { unsigned u; float f; } x; x.u = ((unsigned)s) << 16; return x.f; }

// ---------------- k_prep: fc transpose (1024 blocks) + W transposes (32) + vproj (64) ----------------
__global__ __launch_bounds__(256) void k_prep(
    const float* __restrict__ fc, unsigned short* __restrict__ fcT,
    const float* __restrict__ Q, unsigned short* __restrict__ WTq,
    const float* __restrict__ K, unsigned short* __restrict__ WTk,
    const float* __restrict__ fm, const float* __restrict__ V, float* __restrict__ vproj) {
    int x = blockIdx.x;
    int t = threadIdx.x;
    if (x < 1056) {
        // transpose [R][C] fp32 -> [C][R] bf16
        __shared__ float tile[64][65];
        const float* s; unsigned short* d; int R, C, r0, c0;
        if (x < 1024) {
            int bb = x >> 8, rest = x & 255;
            R = 256; C = 4096;
            r0 = (rest >> 6) * 64; c0 = (rest & 63) * 64;
            s = fc + (long)bb * 256 * 4096; d = fcT + (long)bb * 256 * 4096;
        } else {
            int i = x - 1024;
            int mat = i >> 4, idx = i & 15;
            R = 256; C = 256;
            r0 = (idx >> 2) * 64; c0 = (idx & 3) * 64;
            s = mat ? K : Q; d = mat ? WTk : WTq;
        }
        #pragma unroll
        for (int j = 0; j < 16; ++j) {
            int i = t + 256 * j;
            int r = i >> 6, c = i & 63;
            tile[r][c] = s[(long)(r0 + r) * C + c0 + c];
        }
        __syncthreads();
        #pragma unroll
        for (int j = 0; j < 8; ++j) {
            int i = t + 256 * j;
            int row = i >> 5;
            int pr = i & 31;
            float f0 = tile[2 * pr][row];
            float f1 = tile[2 * pr + 1][row];
            unsigned pack = (unsigned)f2bf(f0) | ((unsigned)f2bf(f1) << 16);
            reinterpret_cast<unsigned*>(d)[(((long)(c0 + row) * R + r0) >> 1) + pr] = pack;
        }
    } else {
        // vproj[b][e][p] = sum_d fm[b][d][p] * V[d][e]
        __shared__ float Vl[32][32];
        __shared__ float fml[32][256];
        int i = x - 1056;
        int b = i >> 4, p0 = (i & 15) * 256;
        #pragma unroll
        for (int j = 0; j < 4; ++j) { int ii = t + 256 * j; Vl[ii >> 5][ii & 31] = V[ii]; }
        for (int j = 0; j < 32; ++j) {
            int ii = t + 256 * j;
            int dd = ii >> 8, c = ii & 255;
            fml[dd][c] = fm[((long)b * DVc + dd) * NP + p0 + c];
        }
        __syncthreads();
        float acc[32];
        #pragma unroll
        for (int e = 0; e < 32; ++e) acc[e] = 0.f;
        for (int dd = 0; dd < 32; ++dd) {
            float fv = fml[dd][t];
            #pragma unroll
            for (int e = 0; e < 32; ++e) acc[e] += fv * Vl[dd][e];
        }
        #pragma unroll
        for (int e = 0; e < 32; ++e) vproj[((long)b * DVc + e) * NP + p0 + t] = acc[e];
    }
}

// ---------------- k_proj: full-e (256) per 64-p tile. grid (64, 8=b*mat) ----------------
// mat==0 -> qT bf16 [b][p][e]; mat==1 -> kproj fp32 [b][e][p]
__global__ __launch_bounds__(256) void k_proj(
    const unsigned short* __restrict__ WTq, const unsigned short* __restrict__ WTk,
    const unsigned short* __restrict__ fcT,
    unsigned short* __restrict__ qT, float* __restrict__ kproj) {
    int t = threadIdx.x;
    int wave = t >> 6, lane = t & 63;
    int y = blockIdx.y;
    int b = y & 3, mat = y >> 2;
    int p0 = blockIdx.x * 64;
    int ln = lane & 15, quad = lane >> 4;
    const unsigned short* WT = mat ? WTk : WTq;
    int e0w = wave * 64;
    const unsigned short* bbase = fcT + ((long)b * NP + p0 + ln) * DKc + quad * 8;
    f32x4 acc[4][4] = {};
    for (int kk = 0; kk < DKc; kk += 32) {
        bf16x8 a[4], bb[4];
        #pragma unroll
        for (int i = 0; i < 4; ++i)
            a[i] = *reinterpret_cast<const bf16x8*>(WT + (long)(e0w + i * 16 + ln) * DKc + quad * 8 + kk);
        #pragma unroll
        for (int j = 0; j < 4; ++j)
            bb[j] = *reinterpret_cast<const bf16x8*>(bbase + (long)j * 16 * DKc + kk);
        #pragma unroll
        for (int i = 0; i < 4; ++i)
            #pragma unroll
            for (int j = 0; j < 4; ++j)
                acc[i][j] = __builtin_amdgcn_mfma_f32_16x16x32_bf16(a[i], bb[j], acc[i][j], 0, 0, 0);
    }
    if (mat == 0) {
        #pragma unroll
        for (int i = 0; i < 4; ++i)
            #pragma unroll
            for (int j = 0; j < 4; ++j)
                #pragma unroll
                for (int r = 0; r < 4; ++r) {
                    int e = e0w + i * 16 + quad * 4 + r, p = p0 + j * 16 + ln;
                    qT[((long)b * NP + p) * DKc + e] = f2bf(acc[i][j][r]);
                }
    } else {
        #pragma unroll
        for (int i = 0; i < 4; ++i)
            #pragma unroll
            for (int j = 0; j < 4; ++j)
                #pragma unroll
                for (int r = 0; r < 4; ++r) {
                    int e = e0w + i * 16 + quad * 4 + r, p = p0 + j * 16 + ln;
                    kproj[((long)b * DKc + e) * NP + p] = acc[i][j][r];
                }
    }
}

// ---------------- k_fused: scores + softmax(w) + ctx + epilogue ----------------
// grid 256: blockIdx.x = b*64 + hrow  (same hrow -> same XCD for L2 k/v sharing)
// 512 threads. scores phase: wq = t&15 (w-quad), eg = t>>4 (e-group of 8).
__global__ __launch_bounds__(512, 2) void k_fused(
    const unsigned short* __restrict__ qT, const float* __restrict__ kproj,
    const float* __restrict__ kbuf, const float* __restrict__ vproj,
    const float* __restrict__ vbuf, const float* __restrict__ fm,
    float* __restrict__ out, float scale) {
    __shared__ float smemf[256 * 68];            // aliased: q-stage [256][68] then red [8][32][68]
    __shared__ float sc[32][68];
    float (*LDSq)[68] = reinterpret_cast<float (*)[68]>(smemf);
    float (*red)[32][68] = reinterpret_cast<float (*)[32][68]>(smemf);
    int t = threadIdx.x;
    int b = blockIdx.x >> 6, hrow = blockIdx.x & 63;
    int p0h = hrow * 64;

    // stage q tile [64p][256e] bf16 -> LDS [e][w] fp32 (conflict-free writes: lanes span p)
    {
        const unsigned short* qtile = qT + ((long)b * NP + p0h) * DKc;
        int ec = t >> 6, p = t & 63;
        #pragma unroll
        for (int s = 0; s < 4; ++s) {
            int e0 = ec * 32 + s * 8;
            bf16x8 v8 = *reinterpret_cast<const bf16x8*>(qtile + (long)p * DKc + e0);
            #pragma unroll
            for (int i = 0; i < 8; ++i) LDSq[e0 + i][p] = bf2f((unsigned short)v8[i]);
        }
    }
    __syncthreads();

    int wq = t & 15, eg = t >> 4;
    // hoist q fragment to registers: q4[j] = q[eg*8+j][wq*4..+3]
    f32x4 q4[8];
    #pragma unroll
    for (int j = 0; j < 8; ++j)
        q4[j] = *reinterpret_cast<const f32x4*>(&LDSq[eg * 8 + j][wq * 4]);
    __syncthreads();   // LDSq dead; red may be written after this point

    // k-stream: acc[m] = partial dot over e in [eg*8, eg*8+8)
    f32x4 acc[NM];
    #pragma unroll
    for (int m = 0; m < NM; ++m) acc[m] = (f32x4){0.f, 0.f, 0.f, 0.f};
    #pragma unroll
    for (int m = 0; m < NM; ++m) {
        const float* kp = (m < 4 ? kproj + (long)m * DKc * NP : kbuf + (long)(m - 4) * DKc * NP)
                          + (long)(eg * 8) * NP + p0h + wq * 4;
        #pragma unroll
        for (int j = 0; j < 8; ++j) {
            f32x4 kv = *reinterpret_cast<const f32x4*>(kp + (long)j * NP);
            acc[m] += q4[j] * kv;
        }
    }
    // reduce over the 4 eg's within each wave (lanes differ in lane>>4)
    #pragma unroll
    for (int m = 0; m < NM; ++m)
        #pragma unroll
        for (int c = 0; c < 4; ++c) {
            float v = acc[m][c];
            v += __shfl_xor(v, 16);
            v += __shfl_xor(v, 32);
            acc[m][c] = v;
        }
    int wave = t >> 6, lane = t & 63;
    if (lane < 16) {
        #pragma unroll
        for (int m = 0; m < NM; ++m)
            *reinterpret_cast<f32x4*>(&red[wave][m][lane * 4]) = acc[m];
    }
    __syncthreads();
    // final reduce over 8 waves -> scores LDS
    {
        int m = t >> 4, w0 = (t & 15) * 4;
        f32x4 s = (f32x4){0.f, 0.f, 0.f, 0.f};
        #pragma unroll
        for (int v = 0; v < 8; ++v) s += *reinterpret_cast<const f32x4*>(&red[v][m][w0]);
        f32x4 sv = s * scale;
        *reinterpret_cast<f32x4*>(&sc[m][w0]) = sv;
    }
    __syncthreads();
    // softmax over w per row m: 8 waves x 4 rows
    {
        #pragma unroll
        for (int r = 0; r < 4; ++r) {
            int m = wave * 4 + r;
            float x = sc[m][lane];
            float mx = x;
            #pragma unroll
            for (int d = 1; d < 64; d <<= 1) mx = fmaxf(mx, __shfl_xor(mx, d));
            float e = __expf(x - mx);
            float sum = e;
            #pragma unroll
            for (int d = 1; d < 64; d <<= 1) sum += __shfl_xor(sum, d);
            sc[m][lane] = e / sum;
        }
    }
    __syncthreads();
    // ctx + epilogue: w = t&63, dg = t>>6 (8 groups x 4 d)
    {
        int w = t & 63, dg = t >> 6;
        f32x4 c = (f32x4){0.f, 0.f, 0.f, 0.f};
        #pragma unroll
        for (int m = 0; m < NM; ++m) {
            float a = sc[m][w];
            const float* vp = (m < 4 ? vproj + (long)m * DVc * NP : vbuf + (long)(m - 4) * DVc * NP)
                              + (long)(dg * 4) * NP + p0h + w;
            #pragma unroll
            for (int i = 0; i < 4; ++i) c[i] += a * vp[(long)i * NP];
        }
        #pragma unroll
        for (int i = 0; i < 4; ++i) {
            long gi = ((long)b * DVc + dg * 4 + i) * NP + p0h + w;
            out[gi] = fm[gi] + 0.5f * c[i];
        }
    }
}

extern "C" void kernel_launch(void* const* d_in, const int* in_sizes, int n_in,
                              void* d_out, int out_size, void* d_ws, size_t ws_size,
                              hipStream_t stream) {
    const float* fc = (const float*)d_in[0];
    const float* fm = (const float*)d_in[1];
    const float* kb = (const float*)d_in[2];
    const float* vb = (const float*)d_in[3];
    const float* Q  = (const float*)d_in[4];
    const float* K  = (const float*)d_in[5];
    const float* V  = (const float*)d_in[6];
    float* out = (float*)d_out;
    char* ws = (char*)d_ws;
    unsigned short* fcT   = (unsigned short*)(ws);                 // 8388608 B
    unsigned short* WTq   = (unsigned short*)(ws + 8388608);       // 131072 B
    unsigned short* WTk   = (unsigned short*)(ws + 8519680);       // 131072 B
    unsigned short* qT    = (unsigned short*)(ws + 8650752);       // 8388608 B
    float*          kproj = (float*)(ws + 17039360);               // 16777216 B
    float*          vproj = (float*)(ws + 33816576);               // 2097152 B
    float scale = (float)(log(135168.0) / log(1000.0) / 16.0);

    hipLaunchKernelGGL(k_prep, dim3(1120), dim3(256), 0, stream,
                       fc, fcT, Q, WTq, K, WTk, fm, V, vproj);
    hipLaunchKernelGGL(k_proj, dim3(64, 8), dim3(256), 0, stream,
                       WTq, WTk, fcT, qT, kproj);
    hipLaunchKernelGGL(k_fused, dim3(256), dim3(512), 0, stream,
                       qT, kproj, kb, vproj, vb, fm, out, scale);
}